// Round 11
// baseline (232.612 us; speedup 1.0000x reference)
//
#include <hip/hip_runtime.h>

typedef __attribute__((ext_vector_type(8))) short bf16x8;
typedef __attribute__((ext_vector_type(4))) short bf16x4;
typedef __attribute__((ext_vector_type(4))) float f32x4;

#define MFMA(a, b, c) __builtin_amdgcn_mfma_f32_16x16x32_bf16(a, b, c, 0, 0, 0)
#define MFMA16(a, b, c) __builtin_amdgcn_mfma_f32_16x16x16bf16_1k(a, b, c, 0, 0, 0)

__device__ __forceinline__ unsigned short f2bf(float f) {
    unsigned u = __builtin_bit_cast(unsigned, f);
    u += 0x7fffu + ((u >> 16) & 1u);
    return (unsigned short)(u >> 16);
}

// async global->LDS DMA, 16B per lane; LDS dest = wave-uniform base + lane*16.
__device__ __forceinline__ void gload16(const unsigned short* g, unsigned short* l) {
    __builtin_amdgcn_global_load_lds(
        (const __attribute__((address_space(1))) void*)g,
        (__attribute__((address_space(3))) void*)l, 16, 0, 0);
}

// pack two fp32 -> two bf16, round-half-up (3 VALU)
__device__ __forceinline__ unsigned pack_bf16(float lo, float hi) {
    unsigned a = __builtin_bit_cast(unsigned, lo) + 0x8000u;
    unsigned b = __builtin_bit_cast(unsigned, hi) + 0x8000u;
    return __builtin_amdgcn_perm(b, a, 0x07060302);
}
// truncating pack (1 VALU); small downward bias cancels in O/rs normalization
__device__ __forceinline__ unsigned pack_bf16_trunc(float lo, float hi) {
    return __builtin_amdgcn_perm(__builtin_bit_cast(unsigned, hi),
                                 __builtin_bit_cast(unsigned, lo), 0x07060302);
}

// ---------------- fused prep: cvt + transposes + rope tables ----------------
// one launch instead of four; whole blocks take a single branch (no divergence).

__global__ __launch_bounds__(256) void prep(const float* __restrict__ x,
                                            const float* __restrict__ wqkv,
                                            const float* __restrict__ wout,
                                            unsigned short* __restrict__ xb,
                                            unsigned short* __restrict__ wqkvT,
                                            unsigned short* __restrict__ woutT,
                                            float* __restrict__ cosT,
                                            float* __restrict__ sinT) {
    __shared__ float tile[32][33];
    const int bid = blockIdx.x, tid = threadIdx.x;
    if (bid < 4096) {                       // x fp32 -> bf16 (4M elems)
        int i = (bid * 256 + tid) * 4;
        float4 f = *(const float4*)(x + i);
        ushort4 u;
        u.x = f2bf(f.x); u.y = f2bf(f.y); u.z = f2bf(f.z); u.w = f2bf(f.w);
        *(ushort4*)(xb + i) = u;
    } else if (bid < 8448 - 256) {          // transposes
        const float* tin; unsigned short* tout;
        int R, C, bx, by;
        if (bid < 4096 + 3072) {
            int idx = bid - 4096;
            tin = wqkv; tout = wqkvT; R = 1024; C = 3072;
            bx = idx % 96; by = idx / 96;
        } else {
            int idx = bid - 7168;
            tin = wout; tout = woutT; R = 1024; C = 1024;
            bx = idx & 31; by = idx >> 5;
        }
        const int c0 = bx * 32, r0 = by * 32;
        const int tr = tid >> 3;
        const int j4 = (tid & 7) * 4;
        float4 f = *(const float4*)(tin + (size_t)(r0 + tr) * C + c0 + j4);
        tile[tr][j4 + 0] = f.x; tile[tr][j4 + 1] = f.y;
        tile[tr][j4 + 2] = f.z; tile[tr][j4 + 3] = f.w;
        __syncthreads();
        ushort4 u;
        u.x = f2bf(tile[j4 + 0][tr]); u.y = f2bf(tile[j4 + 1][tr]);
        u.z = f2bf(tile[j4 + 2][tr]); u.w = f2bf(tile[j4 + 3][tr]);
        *(ushort4*)(tout + (size_t)(c0 + tr) * R + r0 + j4) = u;
    } else {                                // rope tables (libm sincosf: proper
        int i = (bid - 8192) * 256 + tid;   // range reduction; v_sin undefined
        int n = i >> 5, f = i & 31;         // past +-256 revolutions)
        float ang = (float)n * exp2f((float)f * -0.4152410118609203f);
        float s, c;
        sincosf(ang, &s, &c);
        cosT[i] = c; sinT[i] = s;
    }
}

// ---------------- GEMM (A [M,K] bf16) x (Bt [N,K] bf16) ----------------
// m97-style staging (R8-verified). EPI0: RoPE epilogue; q scaled by
// 0.125*log2e (softmax scale + exp->exp2 fold; exp2 bias cancels in O/rs).

template <int EPI>
__global__ __launch_bounds__(256, 3) void gemm_bt(const unsigned short* __restrict__ A,
                                                  const unsigned short* __restrict__ Bt,
                                                  int K, int Ncols,
                                                  unsigned short* __restrict__ oq,
                                                  unsigned short* __restrict__ ok,
                                                  unsigned short* __restrict__ ovt,
                                                  float* __restrict__ of,
                                                  const float* __restrict__ cosT,
                                                  const float* __restrict__ sinT) {
    __shared__ unsigned short As[2][128 * 32];
    __shared__ unsigned short Bs[2][128 * 32];
    const int tid = threadIdx.x;
    const int w = tid >> 6, lane = tid & 63, quad = lane >> 4, cc = lane & 15;
    const int wm = w >> 1, wn = w & 1;
    const int m0 = blockIdx.y * 128, n0 = blockIdx.x * 128;

    size_t aoff[2], boff[2];
#pragma unroll
    for (int t = 0; t < 2; t++) {
        int S = w * 128 + t * 64 + lane;
        int row = S >> 2;
        int c = (S & 3) ^ ((row >> 1) & 3);
        aoff[t] = (size_t)(m0 + row) * K + c * 8;
        boff[t] = (size_t)(n0 + row) * K + c * 8;
    }

#pragma unroll
    for (int t = 0; t < 2; t++) {
        gload16(A + aoff[t], &As[0][(w * 2 + t) * 512]);
        gload16(Bt + boff[t], &Bs[0][(w * 2 + t) * 512]);
    }
    __syncthreads();

    f32x4 acc[4][4] = {};
    const int rpos = (quad ^ ((cc >> 1) & 3)) * 8;
    const int nkt = K >> 5;

    for (int kt = 0; kt < nkt; kt++) {
        const int pb = kt & 1;
        if (kt < nkt - 1) {
            const int ko = (kt + 1) * 32;
#pragma unroll
            for (int t = 0; t < 2; t++) {
                gload16(A + aoff[t] + ko, &As[pb ^ 1][(w * 2 + t) * 512]);
                gload16(Bt + boff[t] + ko, &Bs[pb ^ 1][(w * 2 + t) * 512]);
            }
        }
        bf16x8 af[4], bf[4];
#pragma unroll
        for (int i = 0; i < 4; i++)
            af[i] = *(const bf16x8*)&As[pb][(wm * 64 + i * 16 + cc) * 32 + rpos];
#pragma unroll
        for (int i = 0; i < 4; i++)
            bf[i] = *(const bf16x8*)&Bs[pb][(wn * 64 + i * 16 + cc) * 32 + rpos];
#pragma unroll
        for (int i = 0; i < 4; i++)
#pragma unroll
            for (int j = 0; j < 4; j++)
                acc[i][j] = MFMA(af[i], bf[j], acc[i][j]);
        __syncthreads();
    }

    if (EPI == 0) {
        const int e0 = n0 + wn * 64;
        const int which = e0 >> 10;           // 0=q 1=k 2=v
        const int h = (e0 >> 6) & 15;
        if (which < 2) {
            unsigned short* dst = (which == 0) ? oq : ok;
            const float postscale = (which == 0) ? 0.18033688f : 1.0f;
#pragma unroll
            for (int mf = 0; mf < 4; mf++) {
#pragma unroll
                for (int r = 0; r < 4; r++) {
                    int mg = m0 + wm * 64 + mf * 16 + quad * 4 + r;
                    int nseq = mg & 2047, b = mg >> 11;
                    float vals[4];
#pragma unroll
                    for (int nf = 0; nf < 4; nf++) vals[nf] = acc[mf][nf][r];
                    size_t rowbase = ((size_t)(b * 16 + h) * 2048 + nseq) * 64;
#pragma unroll
                    for (int nf = 0; nf < 4; nf++) {
                        int d = nf * 16 + cc;
                        int f = d & 31;
                        float cs = cosT[nseq * 32 + f];
                        float sn = sinT[nseq * 32 + f];
                        float partner = vals[nf ^ 2];
                        float outv = (vals[nf] * cs +
                                      ((nf < 2) ? -partner : partner) * sn) * postscale;
                        dst[rowbase + d] = f2bf(outv);
                    }
                }
            }
        } else {
#pragma unroll
            for (int mf = 0; mf < 4; mf++) {
                int mg0 = m0 + wm * 64 + mf * 16 + quad * 4;
                int b = mg0 >> 11, nseq = mg0 & 2047;
#pragma unroll
                for (int nf = 0; nf < 4; nf++) {
                    int d = nf * 16 + cc;
                    ushort4 pk;
                    pk.x = f2bf(acc[mf][nf][0]);
                    pk.y = f2bf(acc[mf][nf][1]);
                    pk.z = f2bf(acc[mf][nf][2]);
                    pk.w = f2bf(acc[mf][nf][3]);
                    *(ushort4*)(ovt + ((size_t)(b * 16 + h) * 64 + d) * 2048 + nseq) = pk;
                }
            }
        }
    } else {
#pragma unroll
        for (int mf = 0; mf < 4; mf++)
#pragma unroll
            for (int nf = 0; nf < 4; nf++)
#pragma unroll
                for (int r = 0; r < 4; r++) {
                    int mg = m0 + wm * 64 + mf * 16 + quad * 4 + r;
                    of[(size_t)mg * Ncols + n0 + wn * 64 + nf * 16 + cc] = acc[mf][nf][r];
                }
    }
}

// ---------------- flash attention v6: split-K 4-way, Kt=32 ----------------
// Fixed-max softmax partials are linear: O = sum O_q / sum rs_q. Each quarter
// runs 16 iters of Kt=32 over its 512 positions. LDS = ks+vs = 16KB/block ->
// 8 blocks/CU by LDS; launch_bounds(256,6) keeps VGPR <=84 (~6 blocks res).
// K-tile: 32 rows x 8 chunks = 256 slots = 4 waves x 64 lanes (1 DMA/wave).
// V^T-tile: 64 rows x 4 chunks = 256 slots. XOR chunk swizzles as before.

__global__ __launch_bounds__(256, 6) void attn_quarter(const unsigned short* __restrict__ q,
                                                       const unsigned short* __restrict__ k,
                                                       const unsigned short* __restrict__ vt,
                                                       unsigned short* __restrict__ opart,
                                                       float* __restrict__ rspart) {
    __shared__ unsigned short ks[2][32 * 64];
    __shared__ unsigned short vs[2][64 * 32];
    const int tid = threadIdx.x;
    const int w = tid >> 6, lane = tid & 63, quad = lane >> 4, cc = lane & 15;
    const int bh = blockIdx.x & 31;
    const int qt = (blockIdx.x >> 5) & 15;
    const int quarter = blockIdx.x >> 9;

    // Q fragments (A-layout), q pre-scaled by 0.125*log2e
    const unsigned short* qg = q + ((size_t)bh * 2048 + qt * 128 + w * 32) * 64;
    bf16x8 aq[2][2];
#pragma unroll
    for (int mf = 0; mf < 2; mf++)
#pragma unroll
        for (int kc = 0; kc < 2; kc++)
            aq[mf][kc] = *(const bf16x8*)(qg + (mf * 16 + cc) * 64 + kc * 32 + quad * 8);

    // DMA offsets (one 16B slot per lane per tile)
    const int S = w * 64 + lane;
    const int krow = S >> 3, kc_ = (S & 7) ^ (krow & 7);
    const int koff = krow * 64 + kc_ * 8;            // k rows: stride 64
    const int vrow = S >> 2, vc_ = (S & 3) ^ (vrow & 3);
    const int voff = vrow * 2048 + vc_ * 8;          // vt rows: stride 2048

    const unsigned short* kg0 = k + (size_t)bh * 131072 + quarter * 32768;
    const unsigned short* vg0 = vt + (size_t)bh * 131072 + quarter * 512;

    gload16(kg0 + koff, &ks[0][w * 512]);
    gload16(vg0 + voff, &vs[0][w * 512]);
    __syncthreads();

    f32x4 oacc[2][4] = {};   // O^T partial: oacc[mf][df] reg r = O[m=cc][d=df*16+quad*4+r]
    float rs[2] = {};

    for (int kt = 0; kt < 16; kt++) {
        const int pb = kt & 1;
        if (kt < 15) {
            gload16(kg0 + (kt + 1) * 2048 + koff, &ks[pb ^ 1][w * 512]);
            gload16(vg0 + (kt + 1) * 32 + voff, &vs[pb ^ 1][w * 512]);
        }

        // S'^T = MFMA(K-rows, Q-rows); s' already includes *log2e/8
        f32x4 s2[2][2] = {};
#pragma unroll
        for (int kc = 0; kc < 2; kc++) {
#pragma unroll
            for (int nf = 0; nf < 2; nf++) {
                bf16x8 bk = *(const bf16x8*)&ks[pb][(nf * 16 + cc) * 64 +
                                                    ((kc * 4 + quad) ^ (cc & 7)) * 8];
                s2[0][nf] = MFMA(bk, aq[0][kc], s2[0][nf]);
                s2[1][nf] = MFMA(bk, aq[1][kc], s2[1][nf]);
            }
        }

        // p' = exp2(s'); truncating pack into K=16 B-operand fragments
        bf16x4 pkr[2][2];
#pragma unroll
        for (int mf = 0; mf < 2; mf++) {
#pragma unroll
            for (int nf = 0; nf < 2; nf++) {
                float p0 = __builtin_amdgcn_exp2f(s2[mf][nf][0]);
                float p1 = __builtin_amdgcn_exp2f(s2[mf][nf][1]);
                float p2 = __builtin_amdgcn_exp2f(s2[mf][nf][2]);
                float p3 = __builtin_amdgcn_exp2f(s2[mf][nf][3]);
                rs[mf] += (p0 + p1) + (p2 + p3);
                uint2 u;
                u.x = pack_bf16_trunc(p0, p1);
                u.y = pack_bf16_trunc(p2, p3);
                pkr[mf][nf] = __builtin_bit_cast(bf16x4, u);
            }
        }

        // O^T += V^T x P^T, P direct from registers (K=16 B-operand layout)
#pragma unroll
        for (int nf = 0; nf < 2; nf++) {
#pragma unroll
            for (int df = 0; df < 4; df++) {
                bf16x4 bv = *(const bf16x4*)&vs[pb][(df * 16 + cc) * 32 +
                                                    (((nf * 2 + (quad >> 1)) ^ (cc & 3)) * 8) +
                                                    (quad & 1) * 4];
                oacc[0][df] = MFMA16(bv, pkr[0][nf], oacc[0][df]);
                oacc[1][df] = MFMA16(bv, pkr[1][nf], oacc[1][df]);
            }
        }

        __syncthreads();   // drains this iter's DMA + guards buffer swap
    }

    // reduce rs across the 4 quads (each lane ends with the full quarter-sum)
#pragma unroll
    for (int mf = 0; mf < 2; mf++) {
        rs[mf] += __shfl_xor(rs[mf], 16, 64);
        rs[mf] += __shfl_xor(rs[mf], 32, 64);
    }

    // store bf16 partial O^T (rounded) + fp32 rs
    {
        unsigned short* op = opart +
            ((size_t)(quarter * 32 + bh) * 2048 + qt * 128 + w * 32) * 64;
#pragma unroll
        for (int mf = 0; mf < 2; mf++)
#pragma unroll
            for (int df = 0; df < 4; df++) {
                uint2 u;
                u.x = pack_bf16(oacc[mf][df][0], oacc[mf][df][1]);
                u.y = pack_bf16(oacc[mf][df][2], oacc[mf][df][3]);
                *(uint2*)(op + (size_t)(mf * 16 + cc) * 64 + df * 16 + quad * 4) = u;
            }
        if (lane < 16) {
            float* rp = rspart + (size_t)(quarter * 32 + bh) * 2048 + qt * 128 + w * 32;
            rp[cc] = rs[0];
            rp[16 + cc] = rs[1];
        }
    }
}

// combine: o[b,n,h*64+d] = sum_q O_q / sum_q rs_q, bf16. 8 elems/thread.
__global__ __launch_bounds__(256) void attn_combine(const unsigned short* __restrict__ opart,
                                                    const float* __restrict__ rspart,
                                                    unsigned short* __restrict__ o) {
    int i = blockIdx.x * 256 + threadIdx.x;       // 524288 threads over [32][2048][64]
    int base = i * 8;
    int bh = base >> 17, m = (base >> 6) & 2047, d0 = base & 63;
    float r = 0.0f;
#pragma unroll
    for (int qq = 0; qq < 4; qq++) r += rspart[qq * 65536 + (bh << 11) + m];
    float inv = 1.0f / r;
    float acc[8] = {};
#pragma unroll
    for (int qq = 0; qq < 4; qq++) {
        const unsigned short* op = opart + (size_t)qq * 4194304 + base;
        ushort4 a0 = *(const ushort4*)op, a1 = *(const ushort4*)(op + 4);
        const unsigned short* av = (const unsigned short*)&a0;
        const unsigned short* bv = (const unsigned short*)&a1;
#pragma unroll
        for (int j = 0; j < 4; j++) {
            acc[j] += __builtin_bit_cast(float, (unsigned)av[j] << 16);
            acc[4 + j] += __builtin_bit_cast(float, (unsigned)bv[j] << 16);
        }
    }
    unsigned short res[8];
#pragma unroll
    for (int j = 0; j < 8; j++) res[j] = f2bf(acc[j] * inv);
    unsigned short* dst = o + ((size_t)((bh >> 4) * 2048 + m)) * 1024 + (bh & 15) * 64 + d0;
    *(ushort4*)dst = *(const ushort4*)&res[0];
    *(ushort4*)(dst + 4) = *(const ushort4*)&res[4];
}

// ---------------- launcher ----------------

extern "C" void kernel_launch(void* const* d_in, const int* in_sizes, int n_in,
                              void* d_out, int out_size, void* d_ws, size_t ws_size,
                              hipStream_t stream) {
    const float* x = (const float*)d_in[0];
    const float* w_qkv = (const float*)d_in[1];
    const float* w_out = (const float*)d_in[2];
    float* out = (float*)d_out;

    unsigned short* xb    = (unsigned short*)d_ws;        // 4096*1024
    unsigned short* wqkvT = xb + 4096 * 1024;             // 3072*1024
    unsigned short* woutT = wqkvT + 3072 * 1024;          // 1024*1024
    unsigned short* qb    = woutT + 1024 * 1024;          // 2*16*2048*64
    unsigned short* kb    = qb + 2 * 16 * 2048 * 64;
    unsigned short* vtb   = kb + 2 * 16 * 2048 * 64;
    unsigned short* ob    = vtb + 2 * 16 * 2048 * 64;     // 4096*1024
    float* cosT = (float*)(ob + 4096 * 1024);             // 2048*32 fp32
    float* sinT = cosT + 2048 * 32;
    unsigned short* opart = (unsigned short*)(sinT + 2048 * 32);  // 4*32*2048*64 bf16
    float* rspart = (float*)(opart + 4 * 32 * 2048 * 64);         // 4*32*2048 fp32

    prep<<<8448, 256, 0, stream>>>(x, w_qkv, w_out, xb, wqkvT, woutT, cosT, sinT);
    gemm_bt<0><<<dim3(24, 32), 256, 0, stream>>>(xb, wqkvT, 1024, 3072,
                                                 qb, kb, vtb, nullptr, cosT, sinT);
    attn_quarter<<<2048, 256, 0, stream>>>(qb, kb, vtb, opart, rspart);
    attn_combine<<<2048, 256, 0, stream>>>(opart, rspart, ob);
    gemm_bt<1><<<dim3(8, 32), 256, 0, stream>>>(ob, woutT, 1024, 1024,
                                                nullptr, nullptr, nullptr, out,
                                                nullptr, nullptr);
}

// Round 12
// 193.228 us; speedup vs baseline: 1.2038x; 1.2038x over previous
//
#include <hip/hip_runtime.h>

typedef __attribute__((ext_vector_type(8))) short bf16x8;
typedef __attribute__((ext_vector_type(4))) short bf16x4;
typedef __attribute__((ext_vector_type(4))) float f32x4;

#define MFMA(a, b, c) __builtin_amdgcn_mfma_f32_16x16x32_bf16(a, b, c, 0, 0, 0)
#define MFMA16(a, b, c) __builtin_amdgcn_mfma_f32_16x16x16bf16_1k(a, b, c, 0, 0, 0)

__device__ __forceinline__ unsigned short f2bf(float f) {
    unsigned u = __builtin_bit_cast(unsigned, f);
    u += 0x7fffu + ((u >> 16) & 1u);
    return (unsigned short)(u >> 16);
}

// async global->LDS DMA, 16B per lane; LDS dest = wave-uniform base + lane*16.
__device__ __forceinline__ void gload16(const unsigned short* g, unsigned short* l) {
    __builtin_amdgcn_global_load_lds(
        (const __attribute__((address_space(1))) void*)g,
        (__attribute__((address_space(3))) void*)l, 16, 0, 0);
}

// pack two fp32 -> two bf16, round-half-up (3 VALU)
__device__ __forceinline__ unsigned pack_bf16(float lo, float hi) {
    unsigned a = __builtin_bit_cast(unsigned, lo) + 0x8000u;
    unsigned b = __builtin_bit_cast(unsigned, hi) + 0x8000u;
    return __builtin_amdgcn_perm(b, a, 0x07060302);
}
// truncating pack (1 VALU); small downward bias cancels in O/rs normalization
__device__ __forceinline__ unsigned pack_bf16_trunc(float lo, float hi) {
    return __builtin_amdgcn_perm(__builtin_bit_cast(unsigned, hi),
                                 __builtin_bit_cast(unsigned, lo), 0x07060302);
}

// ---------------- fused prep: cvt + transposes + rope tables ----------------

__global__ __launch_bounds__(256) void prep(const float* __restrict__ x,
                                            const float* __restrict__ wqkv,
                                            const float* __restrict__ wout,
                                            unsigned short* __restrict__ xb,
                                            unsigned short* __restrict__ wqkvT,
                                            unsigned short* __restrict__ woutT,
                                            float* __restrict__ cosT,
                                            float* __restrict__ sinT) {
    __shared__ float tile[32][33];
    const int bid = blockIdx.x, tid = threadIdx.x;
    if (bid < 4096) {                       // x fp32 -> bf16 (4M elems)
        int i = (bid * 256 + tid) * 4;
        float4 f = *(const float4*)(x + i);
        ushort4 u;
        u.x = f2bf(f.x); u.y = f2bf(f.y); u.z = f2bf(f.z); u.w = f2bf(f.w);
        *(ushort4*)(xb + i) = u;
    } else if (bid < 8448 - 256) {          // transposes
        const float* tin; unsigned short* tout;
        int R, C, bx, by;
        if (bid < 4096 + 3072) {
            int idx = bid - 4096;
            tin = wqkv; tout = wqkvT; R = 1024; C = 3072;
            bx = idx % 96; by = idx / 96;
        } else {
            int idx = bid - 7168;
            tin = wout; tout = woutT; R = 1024; C = 1024;
            bx = idx & 31; by = idx >> 5;
        }
        const int c0 = bx * 32, r0 = by * 32;
        const int tr = tid >> 3;
        const int j4 = (tid & 7) * 4;
        float4 f = *(const float4*)(tin + (size_t)(r0 + tr) * C + c0 + j4);
        tile[tr][j4 + 0] = f.x; tile[tr][j4 + 1] = f.y;
        tile[tr][j4 + 2] = f.z; tile[tr][j4 + 3] = f.w;
        __syncthreads();
        ushort4 u;
        u.x = f2bf(tile[j4 + 0][tr]); u.y = f2bf(tile[j4 + 1][tr]);
        u.z = f2bf(tile[j4 + 2][tr]); u.w = f2bf(tile[j4 + 3][tr]);
        *(ushort4*)(tout + (size_t)(c0 + tr) * R + r0 + j4) = u;
    } else {                                // rope tables (libm sincosf: proper
        int i = (bid - 8192) * 256 + tid;   // range reduction; v_sin undefined
        int n = i >> 5, f = i & 31;         // past +-256 revolutions)
        float ang = (float)n * exp2f((float)f * -0.4152410118609203f);
        float s, c;
        sincosf(ang, &s, &c);
        cosT[i] = c; sinT[i] = s;
    }
}

// ---------------- GEMM (A [M,K] bf16) x (Bt [N,K] bf16) ----------------
// m97-style staging (R8-verified). EPI0: RoPE epilogue; q scaled by
// 0.125*log2e (softmax scale + exp->exp2 fold; exp2 bias cancels in O/rs).

template <int EPI>
__global__ __launch_bounds__(256, 3) void gemm_bt(const unsigned short* __restrict__ A,
                                                  const unsigned short* __restrict__ Bt,
                                                  int K, int Ncols,
                                                  unsigned short* __restrict__ oq,
                                                  unsigned short* __restrict__ ok,
                                                  unsigned short* __restrict__ ovt,
                                                  float* __restrict__ of,
                                                  const float* __restrict__ cosT,
                                                  const float* __restrict__ sinT) {
    __shared__ unsigned short As[2][128 * 32];
    __shared__ unsigned short Bs[2][128 * 32];
    const int tid = threadIdx.x;
    const int w = tid >> 6, lane = tid & 63, quad = lane >> 4, cc = lane & 15;
    const int wm = w >> 1, wn = w & 1;
    const int m0 = blockIdx.y * 128, n0 = blockIdx.x * 128;

    size_t aoff[2], boff[2];
#pragma unroll
    for (int t = 0; t < 2; t++) {
        int S = w * 128 + t * 64 + lane;
        int row = S >> 2;
        int c = (S & 3) ^ ((row >> 1) & 3);
        aoff[t] = (size_t)(m0 + row) * K + c * 8;
        boff[t] = (size_t)(n0 + row) * K + c * 8;
    }

#pragma unroll
    for (int t = 0; t < 2; t++) {
        gload16(A + aoff[t], &As[0][(w * 2 + t) * 512]);
        gload16(Bt + boff[t], &Bs[0][(w * 2 + t) * 512]);
    }
    __syncthreads();

    f32x4 acc[4][4] = {};
    const int rpos = (quad ^ ((cc >> 1) & 3)) * 8;
    const int nkt = K >> 5;

    for (int kt = 0; kt < nkt; kt++) {
        const int pb = kt & 1;
        if (kt < nkt - 1) {
            const int ko = (kt + 1) * 32;
#pragma unroll
            for (int t = 0; t < 2; t++) {
                gload16(A + aoff[t] + ko, &As[pb ^ 1][(w * 2 + t) * 512]);
                gload16(Bt + boff[t] + ko, &Bs[pb ^ 1][(w * 2 + t) * 512]);
            }
        }
        bf16x8 af[4], bf[4];
#pragma unroll
        for (int i = 0; i < 4; i++)
            af[i] = *(const bf16x8*)&As[pb][(wm * 64 + i * 16 + cc) * 32 + rpos];
#pragma unroll
        for (int i = 0; i < 4; i++)
            bf[i] = *(const bf16x8*)&Bs[pb][(wn * 64 + i * 16 + cc) * 32 + rpos];
#pragma unroll
        for (int i = 0; i < 4; i++)
#pragma unroll
            for (int j = 0; j < 4; j++)
                acc[i][j] = MFMA(af[i], bf[j], acc[i][j]);
        __syncthreads();
    }

    if (EPI == 0) {
        const int e0 = n0 + wn * 64;
        const int which = e0 >> 10;           // 0=q 1=k 2=v
        const int h = (e0 >> 6) & 15;
        if (which < 2) {
            unsigned short* dst = (which == 0) ? oq : ok;
            const float postscale = (which == 0) ? 0.18033688f : 1.0f;
#pragma unroll
            for (int mf = 0; mf < 4; mf++) {
#pragma unroll
                for (int r = 0; r < 4; r++) {
                    int mg = m0 + wm * 64 + mf * 16 + quad * 4 + r;
                    int nseq = mg & 2047, b = mg >> 11;
                    float vals[4];
#pragma unroll
                    for (int nf = 0; nf < 4; nf++) vals[nf] = acc[mf][nf][r];
                    size_t rowbase = ((size_t)(b * 16 + h) * 2048 + nseq) * 64;
#pragma unroll
                    for (int nf = 0; nf < 4; nf++) {
                        int d = nf * 16 + cc;
                        int f = d & 31;
                        float cs = cosT[nseq * 32 + f];
                        float sn = sinT[nseq * 32 + f];
                        float partner = vals[nf ^ 2];
                        float outv = (vals[nf] * cs +
                                      ((nf < 2) ? -partner : partner) * sn) * postscale;
                        dst[rowbase + d] = f2bf(outv);
                    }
                }
            }
        } else {
#pragma unroll
            for (int mf = 0; mf < 4; mf++) {
                int mg0 = m0 + wm * 64 + mf * 16 + quad * 4;
                int b = mg0 >> 11, nseq = mg0 & 2047;
#pragma unroll
                for (int nf = 0; nf < 4; nf++) {
                    int d = nf * 16 + cc;
                    ushort4 pk;
                    pk.x = f2bf(acc[mf][nf][0]);
                    pk.y = f2bf(acc[mf][nf][1]);
                    pk.z = f2bf(acc[mf][nf][2]);
                    pk.w = f2bf(acc[mf][nf][3]);
                    *(ushort4*)(ovt + ((size_t)(b * 16 + h) * 64 + d) * 2048 + nseq) = pk;
                }
            }
        }
    } else {
#pragma unroll
        for (int mf = 0; mf < 4; mf++)
#pragma unroll
            for (int nf = 0; nf < 4; nf++)
#pragma unroll
                for (int r = 0; r < 4; r++) {
                    int mg = m0 + wm * 64 + mf * 16 + quad * 4 + r;
                    of[(size_t)mg * Ncols + n0 + wn * 64 + nf * 16 + cc] = acc[mf][nf][r];
                }
    }
}

// ---------------- flash attention v6b: split-K 4-way, Kt=32 ----------------
// R11 ERRATA: launch_bounds(256,6) forced VGPR->40, spilling the ~60-reg live
// set (WRITE_SIZE 142MB = spill stores, R4 signature). Bound relaxed to
// (256,4): natural VGPR ~60 -> occupancy limited by min(VGPR 8 waves/EU,
// LDS 16KB -> 8 blocks, grid 2048 -> 8 blocks/CU) = 8 blocks WITHOUT spills.

__global__ __launch_bounds__(256, 4) void attn_quarter(const unsigned short* __restrict__ q,
                                                       const unsigned short* __restrict__ k,
                                                       const unsigned short* __restrict__ vt,
                                                       unsigned short* __restrict__ opart,
                                                       float* __restrict__ rspart) {
    __shared__ unsigned short ks[2][32 * 64];
    __shared__ unsigned short vs[2][64 * 32];
    const int tid = threadIdx.x;
    const int w = tid >> 6, lane = tid & 63, quad = lane >> 4, cc = lane & 15;
    const int bh = blockIdx.x & 31;
    const int qt = (blockIdx.x >> 5) & 15;
    const int quarter = blockIdx.x >> 9;

    // Q fragments (A-layout), q pre-scaled by 0.125*log2e
    const unsigned short* qg = q + ((size_t)bh * 2048 + qt * 128 + w * 32) * 64;
    bf16x8 aq[2][2];
#pragma unroll
    for (int mf = 0; mf < 2; mf++)
#pragma unroll
        for (int kc = 0; kc < 2; kc++)
            aq[mf][kc] = *(const bf16x8*)(qg + (mf * 16 + cc) * 64 + kc * 32 + quad * 8);

    // DMA offsets (one 16B slot per lane per tile)
    const int S = w * 64 + lane;
    const int krow = S >> 3, kc_ = (S & 7) ^ (krow & 7);
    const int koff = krow * 64 + kc_ * 8;            // k rows: stride 64
    const int vrow = S >> 2, vc_ = (S & 3) ^ (vrow & 3);
    const int voff = vrow * 2048 + vc_ * 8;          // vt rows: stride 2048

    const unsigned short* kg0 = k + (size_t)bh * 131072 + quarter * 32768;
    const unsigned short* vg0 = vt + (size_t)bh * 131072 + quarter * 512;

    gload16(kg0 + koff, &ks[0][w * 512]);
    gload16(vg0 + voff, &vs[0][w * 512]);
    __syncthreads();

    f32x4 oacc[2][4] = {};   // O^T partial: oacc[mf][df] reg r = O[m=cc][d=df*16+quad*4+r]
    float rs[2] = {};

    for (int kt = 0; kt < 16; kt++) {
        const int pb = kt & 1;
        if (kt < 15) {
            gload16(kg0 + (kt + 1) * 2048 + koff, &ks[pb ^ 1][w * 512]);
            gload16(vg0 + (kt + 1) * 32 + voff, &vs[pb ^ 1][w * 512]);
        }

        // S'^T = MFMA(K-rows, Q-rows); s' already includes *log2e/8
        f32x4 s2[2][2] = {};
#pragma unroll
        for (int kc = 0; kc < 2; kc++) {
#pragma unroll
            for (int nf = 0; nf < 2; nf++) {
                bf16x8 bk = *(const bf16x8*)&ks[pb][(nf * 16 + cc) * 64 +
                                                    ((kc * 4 + quad) ^ (cc & 7)) * 8];
                s2[0][nf] = MFMA(bk, aq[0][kc], s2[0][nf]);
                s2[1][nf] = MFMA(bk, aq[1][kc], s2[1][nf]);
            }
        }

        // p' = exp2(s'); truncating pack into K=16 B-operand fragments
        bf16x4 pkr[2][2];
#pragma unroll
        for (int mf = 0; mf < 2; mf++) {
#pragma unroll
            for (int nf = 0; nf < 2; nf++) {
                float p0 = __builtin_amdgcn_exp2f(s2[mf][nf][0]);
                float p1 = __builtin_amdgcn_exp2f(s2[mf][nf][1]);
                float p2 = __builtin_amdgcn_exp2f(s2[mf][nf][2]);
                float p3 = __builtin_amdgcn_exp2f(s2[mf][nf][3]);
                rs[mf] += (p0 + p1) + (p2 + p3);
                uint2 u;
                u.x = pack_bf16_trunc(p0, p1);
                u.y = pack_bf16_trunc(p2, p3);
                pkr[mf][nf] = __builtin_bit_cast(bf16x4, u);
            }
        }

        // O^T += V^T x P^T, P direct from registers (K=16 B-operand layout)
#pragma unroll
        for (int nf = 0; nf < 2; nf++) {
#pragma unroll
            for (int df = 0; df < 4; df++) {
                bf16x4 bv = *(const bf16x4*)&vs[pb][(df * 16 + cc) * 32 +
                                                    (((nf * 2 + (quad >> 1)) ^ (cc & 3)) * 8) +
                                                    (quad & 1) * 4];
                oacc[0][df] = MFMA16(bv, pkr[0][nf], oacc[0][df]);
                oacc[1][df] = MFMA16(bv, pkr[1][nf], oacc[1][df]);
            }
        }

        __syncthreads();   // drains this iter's DMA + guards buffer swap
    }

    // reduce rs across the 4 quads (each lane ends with the full quarter-sum)
#pragma unroll
    for (int mf = 0; mf < 2; mf++) {
        rs[mf] += __shfl_xor(rs[mf], 16, 64);
        rs[mf] += __shfl_xor(rs[mf], 32, 64);
    }

    // store bf16 partial O^T (rounded) + fp32 rs
    {
        unsigned short* op = opart +
            ((size_t)(quarter * 32 + bh) * 2048 + qt * 128 + w * 32) * 64;
#pragma unroll
        for (int mf = 0; mf < 2; mf++)
#pragma unroll
            for (int df = 0; df < 4; df++) {
                uint2 u;
                u.x = pack_bf16(oacc[mf][df][0], oacc[mf][df][1]);
                u.y = pack_bf16(oacc[mf][df][2], oacc[mf][df][3]);
                *(uint2*)(op + (size_t)(mf * 16 + cc) * 64 + df * 16 + quad * 4) = u;
            }
        if (lane < 16) {
            float* rp = rspart + (size_t)(quarter * 32 + bh) * 2048 + qt * 128 + w * 32;
            rp[cc] = rs[0];
            rp[16 + cc] = rs[1];
        }
    }
}

// combine: o[b,n,h*64+d] = sum_q O_q / sum_q rs_q, bf16. 8 elems/thread.
__global__ __launch_bounds__(256) void attn_combine(const unsigned short* __restrict__ opart,
                                                    const float* __restrict__ rspart,
                                                    unsigned short* __restrict__ o) {
    int i = blockIdx.x * 256 + threadIdx.x;       // 524288 threads over [32][2048][64]
    int base = i * 8;
    int bh = base >> 17, m = (base >> 6) & 2047, d0 = base & 63;
    float r = 0.0f;
#pragma unroll
    for (int qq = 0; qq < 4; qq++) r += rspart[qq * 65536 + (bh << 11) + m];
    float inv = 1.0f / r;
    float acc[8] = {};
#pragma unroll
    for (int qq = 0; qq < 4; qq++) {
        const unsigned short* op = opart + (size_t)qq * 4194304 + base;
        ushort4 a0 = *(const ushort4*)op, a1 = *(const ushort4*)(op + 4);
        const unsigned short* av = (const unsigned short*)&a0;
        const unsigned short* bv = (const unsigned short*)&a1;
#pragma unroll
        for (int j = 0; j < 4; j++) {
            acc[j] += __builtin_bit_cast(float, (unsigned)av[j] << 16);
            acc[4 + j] += __builtin_bit_cast(float, (unsigned)bv[j] << 16);
        }
    }
    unsigned short res[8];
#pragma unroll
    for (int j = 0; j < 8; j++) res[j] = f2bf(acc[j] * inv);
    unsigned short* dst = o + ((size_t)((bh >> 4) * 2048 + m)) * 1024 + (bh & 15) * 64 + d0;
    *(ushort4*)dst = *(const ushort4*)&res[0];
    *(ushort4*)(dst + 4) = *(const ushort4*)&res[4];
}

// ---------------- launcher ----------------

extern "C" void kernel_launch(void* const* d_in, const int* in_sizes, int n_in,
                              void* d_out, int out_size, void* d_ws, size_t ws_size,
                              hipStream_t stream) {
    const float* x = (const float*)d_in[0];
    const float* w_qkv = (const float*)d_in[1];
    const float* w_out = (const float*)d_in[2];
    float* out = (float*)d_out;

    unsigned short* xb    = (unsigned short*)d_ws;        // 4096*1024
    unsigned short* wqkvT = xb + 4096 * 1024;             // 3072*1024
    unsigned short* woutT = wqkvT + 3072 * 1024;          // 1024*1024
    unsigned short* qb    = woutT + 1024 * 1024;          // 2*16*2048*64
    unsigned short* kb    = qb + 2 * 16 * 2048 * 64;
    unsigned short* vtb   = kb + 2 * 16 * 2048 * 64;
    unsigned short* ob    = vtb + 2 * 16 * 2048 * 64;     // 4096*1024
    float* cosT = (float*)(ob + 4096 * 1024);             // 2048*32 fp32
    float* sinT = cosT + 2048 * 32;
    unsigned short* opart = (unsigned short*)(sinT + 2048 * 32);  // 4*32*2048*64 bf16
    float* rspart = (float*)(opart + 4 * 32 * 2048 * 64);         // 4*32*2048 fp32

    prep<<<8448, 256, 0, stream>>>(x, w_qkv, w_out, xb, wqkvT, woutT, cosT, sinT);
    gemm_bt<0><<<dim3(24, 32), 256, 0, stream>>>(xb, wqkvT, 1024, 3072,
                                                 qb, kb, vtb, nullptr, cosT, sinT);
    attn_quarter<<<2048, 256, 0, stream>>>(qb, kb, vtb, opart, rspart);
    attn_combine<<<2048, 256, 0, stream>>>(opart, rspart, ob);
    gemm_bt<1><<<dim3(8, 32), 256, 0, stream>>>(ob, woutT, 1024, 1024,
                                                nullptr, nullptr, nullptr, out,
                                                nullptr, nullptr);
}